// Round 5
// baseline (879.709 us; speedup 1.0000x reference)
//
#include <hip/hip_runtime.h>
#include <stdint.h>

#define B_ 8
#define C_ 32
#define N_ 4096
#define KOUT 9
#define ROUNDS 17   // dilated output uses sorted positions 0,2,...,16
#define RPB 4       // rows (centers) per block, one wave per row in phase 2

typedef unsigned long long u64;
typedef unsigned int u32;

// monotone float->uint mapping: a<b  <=>  fkey(a)<fkey(b)
__device__ __forceinline__ u32 fkey(float f) {
    u32 u = __float_as_uint(f);
    return u ^ (u32)((((int)u) >> 31) | 0x80000000u);
}

// insert k into sorted slots s0<=s1<=s2 (keep 3 smallest)
__device__ __forceinline__ void ins3(u64 k, u64& s0, u64& s1, u64& s2) {
    bool lt0 = k < s0, lt1 = k < s1, lt2 = k < s2;
    s2 = lt1 ? s1 : (lt2 ? k : s2);
    s1 = lt0 ? s0 : (lt1 ? k : s1);
    s0 = lt0 ? k : s0;
}

// sq[b,n] = np.sum(pts*pts, -1), numpy pairwise 8-acc pattern (bit-exact, proven)
__global__ __launch_bounds__(256) void sq_kernel(const float* __restrict__ x,
                                                 float* __restrict__ sq) {
#pragma clang fp contract(off)
    int gid = blockIdx.x * 256 + threadIdx.x;
    int b = gid >> 12, n = gid & (N_ - 1);
    const float* xp = x + (size_t)b * (C_ * N_) + n;
    float w[C_];
#pragma unroll
    for (int c = 0; c < C_; ++c) { float v = xp[(size_t)c * N_]; w[c] = v * v; }
    float r[8];
#pragma unroll
    for (int j = 0; j < 8; ++j) r[j] = w[j];
#pragma unroll
    for (int i = 8; i < 32; i += 8) {
#pragma unroll
        for (int j = 0; j < 8; ++j) r[j] = r[j] + w[i + j];
    }
    sq[gid] = ((r[0] + r[1]) + (r[2] + r[3])) + ((r[4] + r[5]) + (r[6] + r[7]));
}

__global__ __launch_bounds__(256, 3) void knn_kernel(const float* __restrict__ x,
                                                     const float* __restrict__ sq,
                                                     int* __restrict__ out) {
#pragma clang fp contract(off)
    // per-(row, source-wave, slot, lane) top-3 candidates: 24 KB (vs 64 KB distK)
    __shared__ u64 cand[RPB][4][3][64];
    __shared__ float cenL[C_][RPB];     // centers [c][r]

    const int tid = threadIdx.x;
    const int b = blockIdx.x & 7;               // XCD-batch affinity (proven R2)
    const int i0 = (blockIdx.x >> 3) * RPB;
    const float* xb = x + (size_t)b * (C_ * N_);
    const float* sqb = sq + b * N_;

    if (tid < RPB * C_) {
        int r = tid & (RPB - 1), c = tid >> 2;
        cenL[c][r] = xb[(size_t)c * N_ + (i0 + r)];
    }
    __syncthreads();

    const float sqi0 = sqb[i0 + 0], sqi1 = sqb[i0 + 1],
                sqi2 = sqb[i0 + 2], sqi3 = sqb[i0 + 3];

    // ---- phase 1: thread t owns j = 1024*g + 4*t + u  (g,u in 0..3) ----
    // owner lane of j in phase 2: (j>>2)&63 == t&63  -> clean transpose via cand[]
    float acc[RPB][16];                 // [row][g*4+u], fully static indexing
#pragma unroll
    for (int r = 0; r < RPB; ++r)
#pragma unroll
        for (int q = 0; q < 16; ++q) acc[r][q] = 0.0f;

#pragma unroll 1
    for (int cc = 0; cc < C_; cc += 4) {
        float4 cen[4];                  // cen[e] = rows 0..3 at c=cc+e
#pragma unroll
        for (int e = 0; e < 4; ++e)
            cen[e] = *(const float4*)(&cenL[cc + e][0]);
#pragma unroll
        for (int g = 0; g < 4; ++g) {
            const int jb = (g << 10) + (tid << 2);
            float4 v[4];
#pragma unroll
            for (int e = 0; e < 4; ++e)
                v[e] = *(const float4*)(xb + (size_t)(cc + e) * N_ + jb); // dwordx4, coalesced
#pragma unroll
            for (int e = 0; e < 4; ++e) {
                // numpy einsum chain: c ascending per (row, j)
                acc[0][(g<<2)+0] = __builtin_fmaf(cen[e].x, v[e].x, acc[0][(g<<2)+0]);
                acc[0][(g<<2)+1] = __builtin_fmaf(cen[e].x, v[e].y, acc[0][(g<<2)+1]);
                acc[0][(g<<2)+2] = __builtin_fmaf(cen[e].x, v[e].z, acc[0][(g<<2)+2]);
                acc[0][(g<<2)+3] = __builtin_fmaf(cen[e].x, v[e].w, acc[0][(g<<2)+3]);
                acc[1][(g<<2)+0] = __builtin_fmaf(cen[e].y, v[e].x, acc[1][(g<<2)+0]);
                acc[1][(g<<2)+1] = __builtin_fmaf(cen[e].y, v[e].y, acc[1][(g<<2)+1]);
                acc[1][(g<<2)+2] = __builtin_fmaf(cen[e].y, v[e].z, acc[1][(g<<2)+2]);
                acc[1][(g<<2)+3] = __builtin_fmaf(cen[e].y, v[e].w, acc[1][(g<<2)+3]);
                acc[2][(g<<2)+0] = __builtin_fmaf(cen[e].z, v[e].x, acc[2][(g<<2)+0]);
                acc[2][(g<<2)+1] = __builtin_fmaf(cen[e].z, v[e].y, acc[2][(g<<2)+1]);
                acc[2][(g<<2)+2] = __builtin_fmaf(cen[e].z, v[e].z, acc[2][(g<<2)+2]);
                acc[2][(g<<2)+3] = __builtin_fmaf(cen[e].z, v[e].w, acc[2][(g<<2)+3]);
                acc[3][(g<<2)+0] = __builtin_fmaf(cen[e].w, v[e].x, acc[3][(g<<2)+0]);
                acc[3][(g<<2)+1] = __builtin_fmaf(cen[e].w, v[e].y, acc[3][(g<<2)+1]);
                acc[3][(g<<2)+2] = __builtin_fmaf(cen[e].w, v[e].z, acc[3][(g<<2)+2]);
                acc[3][(g<<2)+3] = __builtin_fmaf(cen[e].w, v[e].w, acc[3][(g<<2)+3]);
            }
        }
    }

    // ---- epilogue: finish dists, keep per-thread top-3 per row, write to LDS ----
    float4 sq4[4];
#pragma unroll
    for (int g = 0; g < 4; ++g)
        sq4[g] = *(const float4*)(sqb + (g << 10) + (tid << 2));

    const int src = tid >> 6, lane0 = tid & 63;
#pragma unroll
    for (int r = 0; r < RPB; ++r) {
        const float sqi = (r == 0) ? sqi0 : (r == 1) ? sqi1 : (r == 2) ? sqi2 : sqi3;
        u64 s0 = ~0ull, s1 = ~0ull, s2 = ~0ull;
#pragma unroll
        for (int g = 0; g < 4; ++g) {
            const int jb = (g << 10) + (tid << 2);
            const float sjx = sq4[g].x, sjy = sq4[g].y, sjz = sq4[g].z, sjw = sq4[g].w;
            // (sq_i - 2*inner) + sq_j, each op rounded once (contract off)
            float d0 = (sqi - 2.0f * acc[r][(g<<2)+0]) + sjx;
            float d1 = (sqi - 2.0f * acc[r][(g<<2)+1]) + sjy;
            float d2 = (sqi - 2.0f * acc[r][(g<<2)+2]) + sjz;
            float d3 = (sqi - 2.0f * acc[r][(g<<2)+3]) + sjw;
            ins3(((u64)fkey(d0) << 32) | (u32)(jb + 0), s0, s1, s2);
            ins3(((u64)fkey(d1) << 32) | (u32)(jb + 1), s0, s1, s2);
            ins3(((u64)fkey(d2) << 32) | (u32)(jb + 2), s0, s1, s2);
            ins3(((u64)fkey(d3) << 32) | (u32)(jb + 3), s0, s1, s2);
        }
        cand[r][src][0][lane0] = s0;
        cand[r][src][1][lane0] = s1;
        cand[r][src][2][lane0] = s2;
    }
    __syncthreads();

    // ---- phase 2: wave w selects top-17 of row w from per-lane top-3 ----
    const int w = tid >> 6, lane = tid & 63;
    u64 K1 = ~0ull, K2 = ~0ull, K3 = ~0ull;
#pragma unroll
    for (int s = 0; s < 4; ++s)
#pragma unroll
        for (int k = 0; k < 3; ++k)
            ins3(cand[w][s][k][lane], K1, K2, K3);

    const float sqiw = sqb[i0 + w];
    u64 lastPop = 0;
    u32 myw = 0;
#pragma unroll 1
    for (int r = 0; r < ROUNDS; ++r) {
        u64 kmin = K1;
#pragma unroll
        for (int off = 32; off >= 1; off >>= 1) {
            u64 o = __shfl_xor(kmin, off);
            kmin = (o < kmin) ? o : kmin;
        }
        u32 win = (u32)kmin;                        // j of winner (tie-break by index)
        if (!(r & 1) && lane == (r >> 1)) myw = win;
        if ((int)((win >> 2) & 63) == lane) {       // owner consumes
            lastPop = kmin;
            K1 = K2; K2 = K3; K3 = ~0ull;
            if (K1 == ~0ull && r < ROUNDS - 1) {
                // rare (~0.5%/row): recompute my 64 dists bit-exactly, take the
                // 3 smallest with packed key > lastPop (pops within a lane are
                // ascending, so skipping by rank==key order is exact)
                u64 t0 = ~0ull, t1 = ~0ull, t2 = ~0ull;
#pragma unroll 1
                for (int m = 0; m < 16; ++m) {
#pragma unroll 1
                    for (int u = 0; u < 4; ++u) {
                        int j = (lane << 2) + (m << 8) + u;
                        float a = 0.0f;
#pragma unroll 1
                        for (int c = 0; c < C_; ++c)
                            a = __builtin_fmaf(cenL[c][w], xb[(size_t)c * N_ + j], a);
                        float d = (sqiw - 2.0f * a) + sqb[j];
                        u64 kk = ((u64)fkey(d) << 32) | (u32)j;
                        if (kk > lastPop) ins3(kk, t0, t1, t2);
                    }
                }
                K1 = t0; K2 = t1; K3 = t2;
            }
        }
    }

    // ---- output: (2, B, N, KOUT) int32 ----
    if (lane < KOUT) {
        int row = b * N_ + i0 + w;
        int o = row * KOUT + lane;
        out[o] = (int)myw;                          // winners at positions 0,2,...,16
        out[B_ * N_ * KOUT + o] = i0 + w;           // center index
    }
}

extern "C" void kernel_launch(void* const* d_in, const int* in_sizes, int n_in,
                              void* d_out, int out_size, void* d_ws, size_t ws_size,
                              hipStream_t stream) {
    const float* x = (const float*)d_in[0];
    float* sq = (float*)d_ws;            // B*N floats = 128 KB
    int* out = (int*)d_out;

    hipLaunchKernelGGL(sq_kernel, dim3(B_ * N_ / 256), dim3(256), 0, stream, x, sq);
    hipLaunchKernelGGL(knn_kernel, dim3(B_ * N_ / RPB), dim3(256), 0, stream, x, sq, out);
}

// Round 6
// 536.150 us; speedup vs baseline: 1.6408x; 1.6408x over previous
//
#include <hip/hip_runtime.h>
#include <stdint.h>

#define B_ 8
#define C_ 32
#define N_ 4096
#define KOUT 9
#define ROUNDS 17   // dilated output uses sorted positions 0,2,...,16
#define RPB 4       // rows (centers) per block; waves 0..3 each select one row
#define TPB 512     // 8 waves: amortize the 64.5 KB LDS over 2x the waves

typedef unsigned long long u64;
typedef unsigned int u32;

// monotone float->uint mapping: a<b  <=>  fkey(a)<fkey(b)
__device__ __forceinline__ u32 fkey(float f) {
    u32 u = __float_as_uint(f);
    return u ^ (u32)((((int)u) >> 31) | 0x80000000u);
}

// sq[b,n] = np.sum(pts*pts, -1), numpy pairwise 8-acc pattern (bit-exact, proven R1)
__global__ __launch_bounds__(256) void sq_kernel(const float* __restrict__ x,
                                                 float* __restrict__ sq) {
#pragma clang fp contract(off)
    int gid = blockIdx.x * 256 + threadIdx.x;
    int b = gid >> 12, n = gid & (N_ - 1);
    const float* xp = x + (size_t)b * (C_ * N_) + n;
    float w[C_];
#pragma unroll
    for (int c = 0; c < C_; ++c) { float v = xp[(size_t)c * N_]; w[c] = v * v; }
    float r[8];
#pragma unroll
    for (int j = 0; j < 8; ++j) r[j] = w[j];
#pragma unroll
    for (int i = 8; i < 32; i += 8) {
#pragma unroll
        for (int j = 0; j < 8; ++j) r[j] = r[j] + w[i + j];
    }
    sq[gid] = ((r[0] + r[1]) + (r[2] + r[3])) + ((r[4] + r[5]) + (r[6] + r[7]));
}

__global__ __launch_bounds__(TPB, 4) void knn_kernel(const float* __restrict__ x,
                                                     const float* __restrict__ sq,
                                                     int* __restrict__ out) {
#pragma clang fp contract(off)
    __shared__ u32 distK[RPB][N_];      // 64 KB fkey keys (full rows: robust rescan)
    __shared__ float cenL[C_][RPB];     // centers [c][r], float4 broadcast reads

    const int tid = threadIdx.x;
    const int b = blockIdx.x & 7;               // XCD-batch affinity (proven R2)
    const int i0 = (blockIdx.x >> 3) * RPB;
    const float* xb = x + (size_t)b * (C_ * N_);
    const float* sqb = sq + b * N_;

    if (tid < RPB * C_) {
        int r = tid & (RPB - 1), c = tid >> 2;
        cenL[c][r] = xb[(size_t)c * N_ + (i0 + r)];
    }
    __syncthreads();

    const float sqi0 = sqb[i0 + 0], sqi1 = sqb[i0 + 1],
                sqi2 = sqb[i0 + 2], sqi3 = sqb[i0 + 3];

    // ---- phase 1: thread t owns j = (g<<11) + 4t + u, g in {0,1}, u in {0..3} ----
    // acc[4 rows][8 j] = 32 VGPRs; ALL indices static (R2/R4 lesson: dynamic -> scratch)
    float acc[RPB][8];
#pragma unroll
    for (int r = 0; r < RPB; ++r)
#pragma unroll
        for (int q = 0; q < 8; ++q) acc[r][q] = 0.0f;

#pragma unroll 1
    for (int cc = 0; cc < C_; cc += 4) {
        float4 cen[4];                  // cen[e] = rows 0..3 at c=cc+e
#pragma unroll
        for (int e = 0; e < 4; ++e)
            cen[e] = *(const float4*)(&cenL[cc + e][0]);
#pragma unroll
        for (int g = 0; g < 2; ++g) {
            const int jb = (g << 11) + (tid << 2);
            float4 v[4];
#pragma unroll
            for (int e = 0; e < 4; ++e)
                v[e] = *(const float4*)(xb + (size_t)(cc + e) * N_ + jb); // dwordx4
#pragma unroll
            for (int e = 0; e < 4; ++e) {
                // numpy einsum chain: c ascending per (row, j) — bit-exactness invariant
                acc[0][(g<<2)+0] = __builtin_fmaf(cen[e].x, v[e].x, acc[0][(g<<2)+0]);
                acc[0][(g<<2)+1] = __builtin_fmaf(cen[e].x, v[e].y, acc[0][(g<<2)+1]);
                acc[0][(g<<2)+2] = __builtin_fmaf(cen[e].x, v[e].z, acc[0][(g<<2)+2]);
                acc[0][(g<<2)+3] = __builtin_fmaf(cen[e].x, v[e].w, acc[0][(g<<2)+3]);
                acc[1][(g<<2)+0] = __builtin_fmaf(cen[e].y, v[e].x, acc[1][(g<<2)+0]);
                acc[1][(g<<2)+1] = __builtin_fmaf(cen[e].y, v[e].y, acc[1][(g<<2)+1]);
                acc[1][(g<<2)+2] = __builtin_fmaf(cen[e].y, v[e].z, acc[1][(g<<2)+2]);
                acc[1][(g<<2)+3] = __builtin_fmaf(cen[e].y, v[e].w, acc[1][(g<<2)+3]);
                acc[2][(g<<2)+0] = __builtin_fmaf(cen[e].z, v[e].x, acc[2][(g<<2)+0]);
                acc[2][(g<<2)+1] = __builtin_fmaf(cen[e].z, v[e].y, acc[2][(g<<2)+1]);
                acc[2][(g<<2)+2] = __builtin_fmaf(cen[e].z, v[e].z, acc[2][(g<<2)+2]);
                acc[2][(g<<2)+3] = __builtin_fmaf(cen[e].z, v[e].w, acc[2][(g<<2)+3]);
                acc[3][(g<<2)+0] = __builtin_fmaf(cen[e].w, v[e].x, acc[3][(g<<2)+0]);
                acc[3][(g<<2)+1] = __builtin_fmaf(cen[e].w, v[e].y, acc[3][(g<<2)+1]);
                acc[3][(g<<2)+2] = __builtin_fmaf(cen[e].w, v[e].z, acc[3][(g<<2)+2]);
                acc[3][(g<<2)+3] = __builtin_fmaf(cen[e].w, v[e].w, acc[3][(g<<2)+3]);
            }
        }
    }

    // ---- epilogue: finish distances, write fkey keys to distK (b128 stores) ----
#pragma unroll
    for (int g = 0; g < 2; ++g) {
        const int jb = (g << 11) + (tid << 2);
        float4 sj = *(const float4*)(sqb + jb);
#pragma unroll
        for (int r = 0; r < RPB; ++r) {
            const float sqi = (r == 0) ? sqi0 : (r == 1) ? sqi1 : (r == 2) ? sqi2 : sqi3;
            // (sq_i - 2*inner) + sq_j, each op rounded once (contract off)
            uint4 k4;
            k4.x = fkey((sqi - 2.0f * acc[r][(g<<2)+0]) + sj.x);
            k4.y = fkey((sqi - 2.0f * acc[r][(g<<2)+1]) + sj.y);
            k4.z = fkey((sqi - 2.0f * acc[r][(g<<2)+2]) + sj.z);
            k4.w = fkey((sqi - 2.0f * acc[r][(g<<2)+3]) + sj.w);
            *(uint4*)(&distK[r][jb]) = k4;
        }
    }
    __syncthreads();

    // ---- phase 2 (R3 verbatim): waves 0..3 select top-17 of their row ----
    const int w = tid >> 6, lane = tid & 63;
    if (w < RPB) {
        u32* drow = distK[w];

        u64 K1 = ~0ull, K2 = ~0ull;      // lane's two smallest packed (key<<32)|j
#pragma unroll 1
        for (int m = 0; m < 64; ++m) {
            int j = lane + (m << 6);     // 2-way bank alias (free), j ascending per lane
            u64 kk = ((u64)drow[j] << 32) | (u32)j;
            if (kk < K1) { K2 = K1; K1 = kk; }
            else if (kk < K2) { K2 = kk; }
        }

        u32 myw = 0;
#pragma unroll 1
        for (int r = 0; r < ROUNDS; ++r) {
            u64 kmin = K1;
#pragma unroll
            for (int off = 32; off >= 1; off >>= 1) {
                u64 o = __shfl_xor(kmin, off);
                kmin = (o < kmin) ? o : kmin;
            }
            u32 win = (u32)kmin;                   // j of winner (tie-break by index)
            if (!(r & 1) && lane == (r >> 1)) myw = win;
            if ((int)(win & 63) == lane) {         // owner consumes
                drow[win] = 0xFFFFFFFFu;
                K1 = K2; K2 = ~0ull;
                if (K1 == ~0ull) {                 // rare: rebuild top-2 from LDS (fast)
#pragma unroll 1
                    for (int m = 0; m < 64; ++m) {
                        int j = lane + (m << 6);
                        u64 kk = ((u64)drow[j] << 32) | (u32)j;
                        if (kk < K1) { K2 = K1; K1 = kk; }
                        else if (kk < K2) { K2 = kk; }
                    }
                }
            }
        }

        // ---- output: (2, B, N, KOUT) int32 ----
        if (lane < KOUT) {
            int row = b * N_ + i0 + w;
            int o = row * KOUT + lane;
            out[o] = (int)myw;                     // winners at positions 0,2,...,16
            out[B_ * N_ * KOUT + o] = i0 + w;      // center index
        }
    }
    // waves 4..7: done (single barrier already passed; exit frees the SIMD)
}

extern "C" void kernel_launch(void* const* d_in, const int* in_sizes, int n_in,
                              void* d_out, int out_size, void* d_ws, size_t ws_size,
                              hipStream_t stream) {
    const float* x = (const float*)d_in[0];
    float* sq = (float*)d_ws;            // B*N floats = 128 KB
    int* out = (int*)d_out;

    hipLaunchKernelGGL(sq_kernel, dim3(B_ * N_ / 256), dim3(256), 0, stream, x, sq);
    hipLaunchKernelGGL(knn_kernel, dim3(B_ * N_ / RPB), dim3(TPB), 0, stream, x, sq, out);
}

// Round 8
// 353.205 us; speedup vs baseline: 2.4906x; 1.5180x over previous
//
#include <hip/hip_runtime.h>
#include <stdint.h>

#define B_ 8
#define C_ 32
#define N_ 4096
#define KOUT 9
#define RPB 4       // rows (centers) per block; waves 0..3 each select one row
#define TPB 512     // 8 waves: amortize the 64.5 KB LDS over 2x the waves

typedef unsigned long long u64;
typedef unsigned int u32;

// monotone float->uint mapping: a<b  <=>  fkey(a)<fkey(b)
__device__ __forceinline__ u32 fkey(float f) {
    u32 u = __float_as_uint(f);
    return u ^ (u32)((((int)u) >> 31) | 0x80000000u);
}

// branchless insert of k into sorted L0<=..<=L5 (keep 6 smallest)
__device__ __forceinline__ void ins6(u64 k, u64& L0, u64& L1, u64& L2,
                                     u64& L3, u64& L4, u64& L5) {
    bool lt0 = k < L0, lt1 = k < L1, lt2 = k < L2,
         lt3 = k < L3, lt4 = k < L4, lt5 = k < L5;
    L5 = lt4 ? L4 : (lt5 ? k : L5);
    L4 = lt3 ? L3 : (lt4 ? k : L4);
    L3 = lt2 ? L2 : (lt3 ? k : L3);
    L2 = lt1 ? L1 : (lt2 ? k : L2);
    L1 = lt0 ? L0 : (lt1 ? k : L1);
    L0 = lt0 ? k : L0;
}

// sq[b,n] = np.sum(pts*pts, -1), numpy pairwise 8-acc pattern (bit-exact, proven R1)
__global__ __launch_bounds__(256) void sq_kernel(const float* __restrict__ x,
                                                 float* __restrict__ sq) {
#pragma clang fp contract(off)
    int gid = blockIdx.x * 256 + threadIdx.x;
    int b = gid >> 12, n = gid & (N_ - 1);
    const float* xp = x + (size_t)b * (C_ * N_) + n;
    float w[C_];
#pragma unroll
    for (int c = 0; c < C_; ++c) { float v = xp[(size_t)c * N_]; w[c] = v * v; }
    float r[8];
#pragma unroll
    for (int j = 0; j < 8; ++j) r[j] = w[j];
#pragma unroll
    for (int i = 8; i < 32; i += 8) {
#pragma unroll
        for (int j = 0; j < 8; ++j) r[j] = r[j] + w[i + j];
    }
    sq[gid] = ((r[0] + r[1]) + (r[2] + r[3])) + ((r[4] + r[5]) + (r[6] + r[7]));
}

__global__ __launch_bounds__(TPB, 4) void knn_kernel(const float* __restrict__ x,
                                                     const float* __restrict__ sq,
                                                     int* __restrict__ out) {
#pragma clang fp contract(off)
    __shared__ u32 distK[RPB][N_];      // 64 KB fkey keys (read-only in phase 2)
    __shared__ float cenL[C_][RPB];     // centers [c][r], float4 broadcast reads

    const int tid = threadIdx.x;
    const int b = blockIdx.x & 7;               // XCD-batch affinity (proven R2)
    const int i0 = (blockIdx.x >> 3) * RPB;
    const float* xb = x + (size_t)b * (C_ * N_);
    const float* sqb = sq + b * N_;

    if (tid < RPB * C_) {
        int r = tid & (RPB - 1), c = tid >> 2;
        cenL[c][r] = xb[(size_t)c * N_ + (i0 + r)];
    }
    __syncthreads();

    const float sqi0 = sqb[i0 + 0], sqi1 = sqb[i0 + 1],
                sqi2 = sqb[i0 + 2], sqi3 = sqb[i0 + 3];

    // ---- phase 1 (R5 verbatim): thread t owns j = (g<<11) + 4t + u ----
    float acc[RPB][8];
#pragma unroll
    for (int r = 0; r < RPB; ++r)
#pragma unroll
        for (int q = 0; q < 8; ++q) acc[r][q] = 0.0f;

#pragma unroll 1
    for (int cc = 0; cc < C_; cc += 4) {
        float4 cen[4];                  // cen[e] = rows 0..3 at c=cc+e
#pragma unroll
        for (int e = 0; e < 4; ++e)
            cen[e] = *(const float4*)(&cenL[cc + e][0]);
#pragma unroll
        for (int g = 0; g < 2; ++g) {
            const int jb = (g << 11) + (tid << 2);
            float4 v[4];
#pragma unroll
            for (int e = 0; e < 4; ++e)
                v[e] = *(const float4*)(xb + (size_t)(cc + e) * N_ + jb); // dwordx4
#pragma unroll
            for (int e = 0; e < 4; ++e) {
                // numpy einsum chain: c ascending per (row, j) — bit-exactness invariant
                acc[0][(g<<2)+0] = __builtin_fmaf(cen[e].x, v[e].x, acc[0][(g<<2)+0]);
                acc[0][(g<<2)+1] = __builtin_fmaf(cen[e].x, v[e].y, acc[0][(g<<2)+1]);
                acc[0][(g<<2)+2] = __builtin_fmaf(cen[e].x, v[e].z, acc[0][(g<<2)+2]);
                acc[0][(g<<2)+3] = __builtin_fmaf(cen[e].x, v[e].w, acc[0][(g<<2)+3]);
                acc[1][(g<<2)+0] = __builtin_fmaf(cen[e].y, v[e].x, acc[1][(g<<2)+0]);
                acc[1][(g<<2)+1] = __builtin_fmaf(cen[e].y, v[e].y, acc[1][(g<<2)+1]);
                acc[1][(g<<2)+2] = __builtin_fmaf(cen[e].y, v[e].z, acc[1][(g<<2)+2]);
                acc[1][(g<<2)+3] = __builtin_fmaf(cen[e].y, v[e].w, acc[1][(g<<2)+3]);
                acc[2][(g<<2)+0] = __builtin_fmaf(cen[e].z, v[e].x, acc[2][(g<<2)+0]);
                acc[2][(g<<2)+1] = __builtin_fmaf(cen[e].z, v[e].y, acc[2][(g<<2)+1]);
                acc[2][(g<<2)+2] = __builtin_fmaf(cen[e].z, v[e].z, acc[2][(g<<2)+2]);
                acc[2][(g<<2)+3] = __builtin_fmaf(cen[e].z, v[e].w, acc[2][(g<<2)+3]);
                acc[3][(g<<2)+0] = __builtin_fmaf(cen[e].w, v[e].x, acc[3][(g<<2)+0]);
                acc[3][(g<<2)+1] = __builtin_fmaf(cen[e].w, v[e].y, acc[3][(g<<2)+1]);
                acc[3][(g<<2)+2] = __builtin_fmaf(cen[e].w, v[e].z, acc[3][(g<<2)+2]);
                acc[3][(g<<2)+3] = __builtin_fmaf(cen[e].w, v[e].w, acc[3][(g<<2)+3]);
            }
        }
    }

    // ---- epilogue: finish distances, write fkey keys to distK (b128 stores) ----
#pragma unroll
    for (int g = 0; g < 2; ++g) {
        const int jb = (g << 11) + (tid << 2);
        float4 sj = *(const float4*)(sqb + jb);
#pragma unroll
        for (int r = 0; r < RPB; ++r) {
            const float sqi = (r == 0) ? sqi0 : (r == 1) ? sqi1 : (r == 2) ? sqi2 : sqi3;
            // (sq_i - 2*inner) + sq_j, each op rounded once (contract off)
            uint4 k4;
            k4.x = fkey((sqi - 2.0f * acc[r][(g<<2)+0]) + sj.x);
            k4.y = fkey((sqi - 2.0f * acc[r][(g<<2)+1]) + sj.y);
            k4.z = fkey((sqi - 2.0f * acc[r][(g<<2)+2]) + sj.z);
            k4.w = fkey((sqi - 2.0f * acc[r][(g<<2)+3]) + sj.w);
            *(uint4*)(&distK[r][jb]) = k4;
        }
    }
    __syncthreads();

    // ---- phase 2: waves 0..3 select sorted top-17 of their row; pop 2/round ----
    // Invariant: at every round start, each lane's list holds its >=2 smallest
    // remaining owned keys (R6 bug: single-valid-entry lanes hid their 5th key).
    const int w = tid >> 6, lane = tid & 63;
    if (w < RPB) {
        const u32* drow = distK[w];

        // per-lane sorted top-6 over owned j's (owner(j) = j&63, 2-way alias free)
        u64 L0 = ~0ull, L1 = ~0ull, L2 = ~0ull, L3 = ~0ull, L4 = ~0ull, L5 = ~0ull;
#pragma unroll 4
        for (int m = 0; m < 64; ++m) {
            int j = lane + (m << 6);
            u64 kk = ((u64)drow[j] << 32) | (u32)j;
            ins6(kk, L0, L1, L2, L3, L4, L5);
        }

        u64 lastPop = 0;
        u32 myw = 0;
#pragma unroll 1
        for (int r = 0; r < KOUT; ++r) {       // 9 rounds x 2 pops = 18 >= 17
            // butterfly min-2 of all lanes' (L0, L1)
            u64 a0 = L0, a1 = L1;
#pragma unroll
            for (int off = 32; off >= 1; off >>= 1) {
                u64 b0 = __shfl_xor(a0, off);
                u64 b1 = __shfl_xor(a1, off);
                u64 lo = (a0 < b0) ? a0 : b0;
                u64 hi = (a0 < b0) ? b0 : a0;
                u64 m1 = (a1 < b1) ? a1 : b1;
                a0 = lo;
                a1 = (hi < m1) ? hi : m1;
            }
            // a0 = sorted position 2r -> output slot r; a1 = position 2r+1 (discard)
            if (lane == r) myw = (u32)a0;

            // consume both winners from their owners' lists
            bool own0 = ((u32)a0 & 63) == (u32)lane;
            bool own1 = ((u32)a1 & 63) == (u32)lane;
            if (own0) { lastPop = a0; L0 = L1; L1 = L2; L2 = L3; L3 = L4; L4 = L5; L5 = ~0ull; }
            if (own1) { lastPop = a1; L0 = L1; L1 = L2; L2 = L3; L3 = L4; L4 = L5; L5 = ~0ull; }
            // REBUILD when <2 valid remain (hidden owned keys always exist).
            // All my unpopped owned keys are > lastPop (proof: an unpopped key
            // smaller than a popped one would have been exposed and popped
            // first), so a fresh rescan with kk > lastPop is exact.
            if ((own0 || own1) && L1 == ~0ull && r < KOUT - 1) {
                L0 = L1 = L2 = L3 = L4 = L5 = ~0ull;
#pragma unroll 1
                for (int m = 0; m < 64; ++m) {
                    int j = lane + (m << 6);
                    u64 kk = ((u64)drow[j] << 32) | (u32)j;
                    if (kk > lastPop) ins6(kk, L0, L1, L2, L3, L4, L5);
                }
            }
        }

        // ---- output: (2, B, N, KOUT) int32 ----
        if (lane < KOUT) {
            int row = b * N_ + i0 + w;
            int o = row * KOUT + lane;
            out[o] = (int)(myw & (N_ - 1));    // j of sorted position 2*lane
            out[B_ * N_ * KOUT + o] = i0 + w;  // center index
        }
    }
    // waves 4..7: done (single barrier already passed; exit frees the SIMD)
}

extern "C" void kernel_launch(void* const* d_in, const int* in_sizes, int n_in,
                              void* d_out, int out_size, void* d_ws, size_t ws_size,
                              hipStream_t stream) {
    const float* x = (const float*)d_in[0];
    float* sq = (float*)d_ws;            // B*N floats = 128 KB
    int* out = (int*)d_out;

    hipLaunchKernelGGL(sq_kernel, dim3(B_ * N_ / 256), dim3(256), 0, stream, x, sq);
    hipLaunchKernelGGL(knn_kernel, dim3(B_ * N_ / RPB), dim3(TPB), 0, stream, x, sq, out);
}